// Round 13
// baseline (254.015 us; speedup 1.0000x reference)
//
#include <hip/hip_runtime.h>
#include <hip/hip_bf16.h>
#include <math.h>

#define B_ 16
#define C_ 64
#define H_ 128
#define W_ 128
#define HW_ (H_*W_)
#define CHW_ (C_*HW_)
#define NTOT_ (B_*CHW_)

typedef __attribute__((ext_vector_type(8))) short short8;
typedef __attribute__((ext_vector_type(4))) float float4v;

__device__ __forceinline__ float leaky(float v) { return v > 0.f ? v : 0.1f * v; }
__device__ __forceinline__ float bs2f(short u) {
    return __uint_as_float(((unsigned)(unsigned short)u) << 16);
}
__device__ __forceinline__ short f2bs(float v) {
    __hip_bfloat16 h = __float2bfloat16(v);
    union { __hip_bfloat16 h; short s; } u; u.h = h; return u.s;
}

// ---------------------------------------------------------------------------
// MERGED setup: [0,4096) = pre (NCHW->NHWC bf16 + rda1 gate), [4096,4192) =
// dyn-kernel MLPs, [4192,4228) = conv weight prepack. One launch, 256 thr.
// ---------------------------------------------------------------------------
__global__ __launch_bounds__(256) void k_setup(
    const float* __restrict__ X, const float* __restrict__ cw,
    const float* __restrict__ cb, __hip_bfloat16* __restrict__ Xn,
    float* __restrict__ G1,
    const float* __restrict__ d,
    const float* __restrict__ k1a, const float* __restrict__ k2a,
    const float* __restrict__ k1b, const float* __restrict__ k2b,
    float* __restrict__ kernA, float* __restrict__ kernB,
    const float* __restrict__ W1, const float* __restrict__ W2,
    __hip_bfloat16* __restrict__ P1, __hip_bfloat16* __restrict__ P2)
{
    __shared__ float sT[64][65];
    __shared__ float pG[4][64];
    __shared__ float hid[64];
    const int bid = blockIdx.x;
    const int tid = threadIdx.x;

    if (bid < 4096) {
        // ---------------- pre: transpose + gate ----------------
        const int b = bid >> 8;
        const int p0 = (bid & 255) * 64;
        #pragma unroll
        for (int i = 0; i < 16; ++i) {
            int idx = i*256 + tid;
            int c = idx >> 6, p = idx & 63;
            sT[c][p] = X[(size_t)b*CHW_ + (size_t)c*HW_ + p0 + p];
        }
        __syncthreads();
        #pragma unroll
        for (int i = 0; i < 16; ++i) {
            int idx = i*256 + tid;
            int p = idx >> 6, c = idx & 63;
            Xn[((size_t)b*HW_ + p0 + p)*64 + c] = __float2bfloat16(sT[c][p]);
        }
        const int cg = tid >> 6, p = tid & 63;
        float part = 0.f;
        #pragma unroll
        for (int c = 0; c < 16; ++c) part = fmaf(sT[cg*16 + c][p], cw[cg*16 + c], part);
        pG[cg][p] = part;
        __syncthreads();
        if (tid < 64) {
            float g = pG[0][tid] + pG[1][tid] + pG[2][tid] + pG[3][tid] + cb[0];
            G1[(size_t)b*HW_ + p0 + tid] = 1.f / (1.f + __expf(-g));
        }
    } else if (bid < 4192) {
        // ---------------- dynamic kernel MLPs ----------------
        const int r2 = bid - 4096;
        const int which = r2 / 48;
        const int rr    = r2 % 48;
        const int b     = rr / 3;
        const int chunk = rr % 3;
        const float* k1 = which ? k1b : k1a;
        const float* k2 = which ? k2b : k2a;
        float* outp = which ? kernB : kernA;
        if (tid < 64) {
            float s = 0.f;
            #pragma unroll
            for (int i = 0; i < 64; ++i) s = fmaf(d[b*64 + i], k1[i*64 + tid], s);
            hid[tid] = leaky(s);
        }
        __syncthreads();
        if (tid < 192) {
            const int o = chunk * 192 + tid;       // 0..575
            float s = 0.f;
            #pragma unroll
            for (int j = 0; j < 64; ++j) s = fmaf(hid[j], k2[j*576 + o], s);
            outp[b*576 + (o % 9)*64 + (o / 9)] = s;
        }
    } else {
        // ---------------- conv weight prepack ----------------
        const int p = bid - 4192;     // 0..35
        const int s = p % 18;
        const int which = p / 18;
        const float* W = which ? W2 : W1;
        __hip_bfloat16* P = which ? P2 : P1;
        const int t = s >> 1, hf = s & 1;
        for (int idx = tid; idx < 2048; idx += 256) {
            const int oc = idx >> 5, kk = idx & 31;
            P[s*2048 + idx] = __float2bfloat16(W[oc*576 + (hf*32 + kk)*9 + t]);
        }
    }
}

// ---------------------------------------------------------------------------
// FUSED: depthwise dynamic RDA (in-LDS, staged) + dense 3x3 conv as implicit
// GEMM on MFMA bf16.  8x16 out px per block, 2048 blocks, 256 thr (4 waves).
// Stage 12x20x64 bf16 halo tile (30720 B).
// XCD-aware swizzle: orig=(s&7)*16+(s>>3) (R10: FETCH −40%).
// LATENCY HIDING (R12):
//  - gate rows prefetched ONE PHASE EARLY (row wv before B1 — drained free
//    by the barrier; rows 4+wv / 8+wv issued under the previous compute) —
//    removes ~2.5 exposed latencies from the barrier-fenced RDA chain.
//  - MFMA B-fragments (global Wpk) software-pipelined bcur/bnxt: step s+1's
//    4 loads issue before step s's MFMAs — 1 exposed L2 latency instead of 18.
// RDA in-place, write/compute-overlapped: C0(r0-3) B [W0||C1(r4-7)] B
// [W1||C2(r8-9,wv<2)] B [W2] B, then 18-step MFMA K-loop, acc[2][4].
// MODE 0: +leaky, NHWC bf16 out, + fused rda2 gate G2.
// MODE 1: +x residual (epilogue loads — tail latency is free), NCHW fp32 out.
// grid (128, B).
// ---------------------------------------------------------------------------
template<int MODE>
__global__ __launch_bounds__(256) void k_rda_conv(
    const __hip_bfloat16* __restrict__ Xn, const float* __restrict__ kernN,
    const float* __restrict__ G, const __hip_bfloat16* __restrict__ Wpk,
    const float* __restrict__ bias, const float* __restrict__ Xres,
    const float* __restrict__ Gcw, const float* __restrict__ Gcb,
    __hip_bfloat16* __restrict__ OutN, float* __restrict__ OutF,
    float* __restrict__ G2)
{
    __shared__ __align__(16) short sA[12*20*64];   // 30720 B
    const int tid = threadIdx.x;
    const int b = blockIdx.y;
    // XCD-aware bijective swizzle on [0,128)
    const int orig = ((blockIdx.x & 7) << 4) | (blockIdx.x >> 3);
    const int h0 = (orig >> 3) * 8;                // 16 h-tiles
    const int w0 = (orig & 7) * 16;                // 8 w-tiles
    const int lane = tid & 63;
    const int wv = tid >> 6;              // 0..3
    const int l15 = lane & 15;
    const int lq = lane >> 4;

    // ---- stage X halo tile (12x20), XOR c-chunk swizzle, zero-padded OOB
    const short* Xs = (const short*)Xn;
    for (int idx = tid; idx < 1920; idx += 256) {
        const int cc = idx & 7;
        const int w = (idx >> 3) % 20;
        const int r = idx / 160;
        const int gh = h0 - 2 + r;
        const int gw = w0 - 2 + w;
        uint4 v = make_uint4(0, 0, 0, 0);
        if ((unsigned)gh < (unsigned)H_ && (unsigned)gw < (unsigned)W_)
            v = *(const uint4*)(Xs + (((size_t)b*H_ + gh)*W_ + gw)*64 + cc*8);
        *(uint4*)(sA + ((r*20 + w)*64 + ((cc ^ (w & 7)) * 8))) = v;
    }

    // per-lane (=channel) dynamic dw kernel
    float k9[9];
    #pragma unroll
    for (int t = 0; t < 9; ++t) k9[t] = kernN[((size_t)b*9 + t)*64 + lane];

    // per-lane swizzled channel offsets, one per (col & 7)
    int loff[8];
    #pragma unroll
    for (int jc = 0; jc < 8; ++jc)
        loff[jc] = (((lane >> 3) ^ jc) << 3) + (lane & 7);

    // gate-row prefetch (wave-uniform contiguous fp32, tiny)
    auto load_gate = [&](int r, float* gv) {
        const int gh = h0 - 1 + r;
        if ((unsigned)gh < (unsigned)H_) {
            const float* Gp = G + (size_t)b*HW_ + (size_t)gh*W_ + (w0 - 1);
            #pragma unroll
            for (int w = 0; w < 18; ++w) {
                const int gw = w0 - 1 + w;
                gv[w] = ((unsigned)gw < (unsigned)W_) ? Gp[w] : 0.f;
            }
        } else {
            #pragma unroll
            for (int w = 0; w < 18; ++w) gv[w] = 0.f;
        }
    };

    // row compute: out = leaky(leaky(dw3x3(X))*M + X) for slot r (18 cols)
    auto compute_row = [&](int r, const float* gv, float* outv) {
        const int gh = h0 - 1 + r;                 // global image row
        if ((unsigned)gh < (unsigned)H_) {
            #pragma unroll
            for (int w = 0; w < 18; ++w) outv[w] = 0.f;
            const short* r0 = sA + (r*20)*64;
            const short* r1 = r0 + 20*64;
            const short* r2 = r1 + 20*64;
            float c1p = 0.f;                        // center-value history
            #pragma unroll
            for (int j = 0; j < 20; ++j) {
                const int off = j*64 + loff[j & 7];
                const float c0 = bs2f(r0[off]);
                const float c1 = bs2f(r1[off]);
                const float c2 = bs2f(r2[off]);
                #pragma unroll
                for (int dw = 0; dw < 3; ++dw) {
                    const int w = j - dw;
                    if (w >= 0 && w < 18)
                        outv[w] = fmaf(c0, k9[dw],
                                  fmaf(c1, k9[3+dw],
                                  fmaf(c2, k9[6+dw], outv[w])));
                }
                const int wf = j - 2;               // finalize column wf
                if (wf >= 0) {
                    const int gw = w0 - 1 + wf;
                    float val = 0.f;
                    if ((unsigned)gw < (unsigned)W_)
                        val = leaky(leaky(outv[wf]) * gv[wf] + c1p);
                    outv[wf] = val;
                }
                c1p = c1;                           // center of col j for wf=j-1
            }
        } else {
            #pragma unroll
            for (int w = 0; w < 18; ++w) outv[w] = 0.f;  // conv zero-pad row
        }
    };
    auto write_rowf = [&](int r, const float* ov) {
        short* wp = sA + (r*20)*64;
        #pragma unroll
        for (int w = 0; w < 18; ++w)
            wp[w*64 + loff[w & 7]] = f2bs(ov[w]);
    };

    // ---- in-LDS RDA, gate rows prefetched one phase early:
    float gv0[18], gv1[18], outv[18];
    load_gate(wv, gv0);                    // drains free at B1
    __syncthreads();                       // B1: stage complete
    load_gate(4 + wv, gv1);                // hidden under C0
    compute_row(wv, gv0, outv);            // C0: rows 0..3
    __syncthreads();                       // B2
    write_rowf(wv, outv);
    load_gate(8 + wv, gv0);                // hidden under C1
    compute_row(4 + wv, gv1, outv);        // C1: rows 4..7
    __syncthreads();                       // B3
    write_rowf(4 + wv, outv);
    if (wv < 2) compute_row(8 + wv, gv0, outv);   // C2: rows 8,9
    __syncthreads();                       // B4
    if (wv < 2) write_rowf(8 + wv, outv);
    __syncthreads();                       // B5: RDA tile complete

    // ---- MFMA implicit-GEMM K-loop (reads slots [0..9][0..17], stride 20)
    float4v acc[2][4];
    #pragma unroll
    for (int i = 0; i < 2; ++i)
        #pragma unroll
        for (int j = 0; j < 4; ++j) acc[i][j] = (float4v)0.f;

    const short* Wp = (const short*)Wpk;
    const int boff = l15*32 + lq*8;        // B-frag offset within a K-step

    // software-pipelined B-fragments: one exposed L2 latency, not 18
    short8 bcur[4], bnxt[4];
    #pragma unroll
    for (int nt = 0; nt < 4; ++nt)
        bcur[nt] = *(const short8*)(Wp + nt*512 + boff);

    #pragma unroll
    for (int s = 0; s < 18; ++s) {
        if (s < 17) {
            #pragma unroll
            for (int nt = 0; nt < 4; ++nt)
                bnxt[nt] = *(const short8*)(Wp + (size_t)(s+1)*2048 + nt*512 + boff);
        }
        const int t = s >> 1, hf = s & 1;
        const int dh = t / 3, dwx = t % 3;
        short8 afr[2];
        #pragma unroll
        for (int mt = 0; mt < 2; ++mt) {
            const int r = wv*2 + mt + dh;
            const int w = l15 + dwx;
            const int chunk = (hf*4 + lq) ^ (w & 7);
            afr[mt] = *(const short8*)(sA + ((r*20 + w)*64 + chunk*8));
        }
        #pragma unroll
        for (int mt = 0; mt < 2; ++mt)
            #pragma unroll
            for (int nt = 0; nt < 4; ++nt)
                acc[mt][nt] = __builtin_amdgcn_mfma_f32_16x16x32_bf16(
                    afr[mt], bcur[nt], acc[mt][nt], 0, 0, 0);
        #pragma unroll
        for (int nt = 0; nt < 4; ++nt) bcur[nt] = bnxt[nt];
    }

    // ---- epilogue
    float bs[4], cwv[4], cbv = 0.f;
    #pragma unroll
    for (int nt = 0; nt < 4; ++nt) bs[nt] = bias[nt*16 + l15];
    if (MODE == 0) {
        #pragma unroll
        for (int nt = 0; nt < 4; ++nt) cwv[nt] = Gcw[nt*16 + l15];
        cbv = Gcb[0];
    }

    #pragma unroll
    for (int mt = 0; mt < 2; ++mt) {
        const int pr = wv*2 + mt;              // 0..7
        if (MODE == 0) {
            float vv[4][4];
            #pragma unroll
            for (int nt = 0; nt < 4; ++nt)
                #pragma unroll
                for (int rg = 0; rg < 4; ++rg)
                    vv[nt][rg] = leaky(acc[mt][nt][rg] + bs[nt]);
            #pragma unroll
            for (int nt = 0; nt < 4; ++nt) {
                const int n = nt*16 + l15;
                #pragma unroll
                for (int rg = 0; rg < 4; ++rg) {
                    const int pw = lq*4 + rg;
                    OutN[(((size_t)b*H_ + h0 + pr)*W_ + w0 + pw)*64 + n] =
                        __float2bfloat16(vv[nt][rg]);
                }
            }
            // fused rda2 gate: reduce 64 oc = 4 nt (in-lane) x 16 l15 (shfl)
            #pragma unroll
            for (int rg = 0; rg < 4; ++rg) {
                float p = vv[0][rg]*cwv[0] + vv[1][rg]*cwv[1]
                        + vv[2][rg]*cwv[2] + vv[3][rg]*cwv[3];
                p += __shfl_xor(p, 1);
                p += __shfl_xor(p, 2);
                p += __shfl_xor(p, 4);
                p += __shfl_xor(p, 8);
                if (l15 == 0)
                    G2[(size_t)b*HW_ + (size_t)(h0 + pr)*W_ + w0 + lq*4 + rg] =
                        1.f / (1.f + __expf(-(p + cbv)));
            }
        } else {
            #pragma unroll
            for (int nt = 0; nt < 4; ++nt) {
                const int n = nt*16 + l15;
                const size_t base = ((size_t)(b*64 + n)*H_ + h0 + pr)*W_ + w0 + lq*4;
                const float4 xr = *(const float4*)(Xres + base);
                float4 v;
                v.x = acc[mt][nt][0] + bs[nt] + xr.x;
                v.y = acc[mt][nt][1] + bs[nt] + xr.y;
                v.z = acc[mt][nt][2] + bs[nt] + xr.z;
                v.w = acc[mt][nt][3] + bs[nt] + xr.w;
                *(float4*)(OutF + base) = v;
            }
        }
    }
}

// ---------------------------------------------------------------------------
extern "C" void kernel_launch(void* const* d_in, const int* in_sizes, int n_in,
                              void* d_out, int out_size, void* d_ws, size_t ws_size,
                              hipStream_t stream)
{
    const float* x       = (const float*)d_in[0];
    const float* d       = (const float*)d_in[1];
    const float* da1_k1  = (const float*)d_in[2];
    const float* da1_k2  = (const float*)d_in[3];
    const float* da1_cw  = (const float*)d_in[4];
    const float* da1_cb  = (const float*)d_in[5];
    const float* da2_k1  = (const float*)d_in[6];
    const float* da2_k2  = (const float*)d_in[7];
    const float* da2_cw  = (const float*)d_in[8];
    const float* da2_cb  = (const float*)d_in[9];
    const float* conv1_w = (const float*)d_in[10];
    const float* conv1_b = (const float*)d_in[11];
    const float* conv2_w = (const float*)d_in[12];
    const float* conv2_b = (const float*)d_in[13];
    float* out = (float*)d_out;

    __hip_bfloat16* bufA = (__hip_bfloat16*)d_ws;      // NTOT_ bf16
    __hip_bfloat16* bufB = bufA + NTOT_;               // NTOT_ bf16
    float* kernA = (float*)(bufB + NTOT_);             // 16*576 fp32
    float* kernB = kernA + 16*576;
    __hip_bfloat16* wpk1 = (__hip_bfloat16*)(kernB + 16*576);  // 18*64*32
    __hip_bfloat16* wpk2 = wpk1 + 18*64*32;
    float* G1 = (float*)(wpk2 + 18*64*32);             // B*HW fp32
    float* G2 = G1 + (size_t)B_*HW_;                   // B*HW fp32

    // merged setup: pre (+rda1 gate) | dyn MLPs | weight prepack
    k_setup<<<dim3(4228), dim3(256), 0, stream>>>(
        x, da1_cw, da1_cb, bufA, G1,
        d, da1_k1, da1_k2, da2_k1, da2_k2, kernA, kernB,
        conv1_w, conv2_w, wpk1, wpk2);
    // fused rda1 + conv1 (+leaky, + rda2 gate): bufA -> bufB (NHWC bf16), G2
    k_rda_conv<0><<<dim3(128, B_), dim3(256), 0, stream>>>(
        bufA, kernA, G1, wpk1, conv1_b, nullptr, da2_cw, da2_cb, bufB, nullptr, G2);
    // fused rda2 + conv2 + x residual -> out (NCHW fp32)
    k_rda_conv<1><<<dim3(128, B_), dim3(256), 0, stream>>>(
        bufB, kernB, G2, wpk2, conv2_b, x, nullptr, nullptr, nullptr, out, nullptr);
}

// Round 14
// 246.683 us; speedup vs baseline: 1.0297x; 1.0297x over previous
//
#include <hip/hip_runtime.h>
#include <hip/hip_bf16.h>
#include <math.h>

#define B_ 16
#define C_ 64
#define H_ 128
#define W_ 128
#define HW_ (H_*W_)
#define CHW_ (C_*HW_)
#define NTOT_ (B_*CHW_)

typedef __attribute__((ext_vector_type(8))) short short8;
typedef __attribute__((ext_vector_type(4))) float float4v;

__device__ __forceinline__ float leaky(float v) { return v > 0.f ? v : 0.1f * v; }
__device__ __forceinline__ float bs2f(short u) {
    return __uint_as_float(((unsigned)(unsigned short)u) << 16);
}
__device__ __forceinline__ short f2bs(float v) {
    __hip_bfloat16 h = __float2bfloat16(v);
    union { __hip_bfloat16 h; short s; } u; u.h = h; return u.s;
}

// ---------------------------------------------------------------------------
// MERGED setup: [0,4096) = pre (NCHW->NHWC bf16 + rda1 gate), [4096,4192) =
// dyn-kernel MLPs, [4192,4228) = conv weight prepack. One launch, 256 thr.
// ---------------------------------------------------------------------------
__global__ __launch_bounds__(256) void k_setup(
    const float* __restrict__ X, const float* __restrict__ cw,
    const float* __restrict__ cb, __hip_bfloat16* __restrict__ Xn,
    float* __restrict__ G1,
    const float* __restrict__ d,
    const float* __restrict__ k1a, const float* __restrict__ k2a,
    const float* __restrict__ k1b, const float* __restrict__ k2b,
    float* __restrict__ kernA, float* __restrict__ kernB,
    const float* __restrict__ W1, const float* __restrict__ W2,
    __hip_bfloat16* __restrict__ P1, __hip_bfloat16* __restrict__ P2)
{
    __shared__ float sT[64][65];
    __shared__ float pG[4][64];
    __shared__ float hid[64];
    const int bid = blockIdx.x;
    const int tid = threadIdx.x;

    if (bid < 4096) {
        // ---------------- pre: transpose + gate ----------------
        const int b = bid >> 8;
        const int p0 = (bid & 255) * 64;
        #pragma unroll
        for (int i = 0; i < 16; ++i) {
            int idx = i*256 + tid;
            int c = idx >> 6, p = idx & 63;
            sT[c][p] = X[(size_t)b*CHW_ + (size_t)c*HW_ + p0 + p];
        }
        __syncthreads();
        #pragma unroll
        for (int i = 0; i < 16; ++i) {
            int idx = i*256 + tid;
            int p = idx >> 6, c = idx & 63;
            Xn[((size_t)b*HW_ + p0 + p)*64 + c] = __float2bfloat16(sT[c][p]);
        }
        const int cg = tid >> 6, p = tid & 63;
        float part = 0.f;
        #pragma unroll
        for (int c = 0; c < 16; ++c) part = fmaf(sT[cg*16 + c][p], cw[cg*16 + c], part);
        pG[cg][p] = part;
        __syncthreads();
        if (tid < 64) {
            float g = pG[0][tid] + pG[1][tid] + pG[2][tid] + pG[3][tid] + cb[0];
            G1[(size_t)b*HW_ + p0 + tid] = 1.f / (1.f + __expf(-g));
        }
    } else if (bid < 4192) {
        // ---------------- dynamic kernel MLPs ----------------
        const int r2 = bid - 4096;
        const int which = r2 / 48;
        const int rr    = r2 % 48;
        const int b     = rr / 3;
        const int chunk = rr % 3;
        const float* k1 = which ? k1b : k1a;
        const float* k2 = which ? k2b : k2a;
        float* outp = which ? kernB : kernA;
        if (tid < 64) {
            float s = 0.f;
            #pragma unroll
            for (int i = 0; i < 64; ++i) s = fmaf(d[b*64 + i], k1[i*64 + tid], s);
            hid[tid] = leaky(s);
        }
        __syncthreads();
        if (tid < 192) {
            const int o = chunk * 192 + tid;       // 0..575
            float s = 0.f;
            #pragma unroll
            for (int j = 0; j < 64; ++j) s = fmaf(hid[j], k2[j*576 + o], s);
            outp[b*576 + (o % 9)*64 + (o / 9)] = s;
        }
    } else {
        // ---------------- conv weight prepack ----------------
        const int p = bid - 4192;     // 0..35
        const int s = p % 18;
        const int which = p / 18;
        const float* W = which ? W2 : W1;
        __hip_bfloat16* P = which ? P2 : P1;
        const int t = s >> 1, hf = s & 1;
        for (int idx = tid; idx < 2048; idx += 256) {
            const int oc = idx >> 5, kk = idx & 31;
            P[s*2048 + idx] = __float2bfloat16(W[oc*576 + (hf*32 + kk)*9 + t]);
        }
    }
}

// ---------------------------------------------------------------------------
// FUSED: depthwise dynamic RDA (in-LDS, staged) + dense 3x3 conv as implicit
// GEMM on MFMA bf16.  8x16 out px per block, 2048 blocks, 256 thr (4 waves).
// Stage 12x20x64 bf16 halo tile (30720 B).
// XCD-aware swizzle: orig=(s&7)*16+(s>>3) (R10: FETCH −40%).
// R14 A/B: gate loads back IN compute_row (R12's pre-barrier gate prefetch
// regressed mode0 55->91 — same pathology as R10: loads upstream of a
// barrier-gated vmcnt(0) drain stall every wave).  KEPT from R12: MFMA
// B-fragments software-pipelined bcur/bnxt (loads live only in the
// barrier-free K-loop region — 1 exposed L2 latency instead of 18).
// RDA in-place, write/compute-overlapped: C0(r0-3) B [W0||C1(r4-7)] B
// [W1||C2(r8-9,wv<2)] B [W2] B, then 18-step MFMA K-loop, acc[2][4].
// MODE 0: +leaky, NHWC bf16 out, + fused rda2 gate G2.
// MODE 1: +x residual (epilogue loads — tail latency is free), NCHW fp32 out.
// grid (128, B).
// ---------------------------------------------------------------------------
template<int MODE>
__global__ __launch_bounds__(256) void k_rda_conv(
    const __hip_bfloat16* __restrict__ Xn, const float* __restrict__ kernN,
    const float* __restrict__ G, const __hip_bfloat16* __restrict__ Wpk,
    const float* __restrict__ bias, const float* __restrict__ Xres,
    const float* __restrict__ Gcw, const float* __restrict__ Gcb,
    __hip_bfloat16* __restrict__ OutN, float* __restrict__ OutF,
    float* __restrict__ G2)
{
    __shared__ __align__(16) short sA[12*20*64];   // 30720 B
    const int tid = threadIdx.x;
    const int b = blockIdx.y;
    // XCD-aware bijective swizzle on [0,128)
    const int orig = ((blockIdx.x & 7) << 4) | (blockIdx.x >> 3);
    const int h0 = (orig >> 3) * 8;                // 16 h-tiles
    const int w0 = (orig & 7) * 16;                // 8 w-tiles
    const int lane = tid & 63;
    const int wv = tid >> 6;              // 0..3
    const int l15 = lane & 15;
    const int lq = lane >> 4;

    // ---- stage X halo tile (12x20), XOR c-chunk swizzle, zero-padded OOB
    const short* Xs = (const short*)Xn;
    for (int idx = tid; idx < 1920; idx += 256) {
        const int cc = idx & 7;
        const int w = (idx >> 3) % 20;
        const int r = idx / 160;
        const int gh = h0 - 2 + r;
        const int gw = w0 - 2 + w;
        uint4 v = make_uint4(0, 0, 0, 0);
        if ((unsigned)gh < (unsigned)H_ && (unsigned)gw < (unsigned)W_)
            v = *(const uint4*)(Xs + (((size_t)b*H_ + gh)*W_ + gw)*64 + cc*8);
        *(uint4*)(sA + ((r*20 + w)*64 + ((cc ^ (w & 7)) * 8))) = v;
    }

    // per-lane (=channel) dynamic dw kernel
    float k9[9];
    #pragma unroll
    for (int t = 0; t < 9; ++t) k9[t] = kernN[((size_t)b*9 + t)*64 + lane];

    // per-lane swizzled channel offsets, one per (col & 7)
    int loff[8];
    #pragma unroll
    for (int jc = 0; jc < 8; ++jc)
        loff[jc] = (((lane >> 3) ^ jc) << 3) + (lane & 7);

    // row compute: out = leaky(leaky(dw3x3(X))*M + X) for slot r (18 cols)
    auto compute_row = [&](int r, float* outv) {
        const int gh = h0 - 1 + r;                 // global image row
        if ((unsigned)gh < (unsigned)H_) {
            // gate row loaded here (wave-uniform, batched) — only the
            // consuming wave waits; overlapped with its own FMA work
            float gv[18];
            const float* Gp = G + (size_t)b*HW_ + (size_t)gh*W_ + (w0 - 1);
            #pragma unroll
            for (int w = 0; w < 18; ++w) {
                const int gw = w0 - 1 + w;
                gv[w] = ((unsigned)gw < (unsigned)W_) ? Gp[w] : 0.f;
            }
            #pragma unroll
            for (int w = 0; w < 18; ++w) outv[w] = 0.f;
            const short* r0 = sA + (r*20)*64;
            const short* r1 = r0 + 20*64;
            const short* r2 = r1 + 20*64;
            float c1p = 0.f;                        // center-value history
            #pragma unroll
            for (int j = 0; j < 20; ++j) {
                const int off = j*64 + loff[j & 7];
                const float c0 = bs2f(r0[off]);
                const float c1 = bs2f(r1[off]);
                const float c2 = bs2f(r2[off]);
                #pragma unroll
                for (int dw = 0; dw < 3; ++dw) {
                    const int w = j - dw;
                    if (w >= 0 && w < 18)
                        outv[w] = fmaf(c0, k9[dw],
                                  fmaf(c1, k9[3+dw],
                                  fmaf(c2, k9[6+dw], outv[w])));
                }
                const int wf = j - 2;               // finalize column wf
                if (wf >= 0) {
                    const int gw = w0 - 1 + wf;
                    float val = 0.f;
                    if ((unsigned)gw < (unsigned)W_)
                        val = leaky(leaky(outv[wf]) * gv[wf] + c1p);
                    outv[wf] = val;
                }
                c1p = c1;                           // center of col j for wf=j-1
            }
        } else {
            #pragma unroll
            for (int w = 0; w < 18; ++w) outv[w] = 0.f;  // conv zero-pad row
        }
    };
    auto write_rowf = [&](int r, const float* ov) {
        short* wp = sA + (r*20)*64;
        #pragma unroll
        for (int w = 0; w < 18; ++w)
            wp[w*64 + loff[w & 7]] = f2bs(ov[w]);
    };

    __syncthreads();     // B1: stage complete

    // ---- in-LDS RDA, 10 output rows, write/compute-overlapped:
    // C0(r 0-3) B [W0||C1(r 4-7)] B [W1||C2(r 8-9, wv<2)] B [W2] B
    float outv[18];
    compute_row(wv, outv);                 // rows 0..3
    __syncthreads();                       // B2
    write_rowf(wv, outv);
    compute_row(4 + wv, outv);             // rows 4..7
    __syncthreads();                       // B3
    write_rowf(4 + wv, outv);
    if (wv < 2) compute_row(8 + wv, outv); // rows 8,9
    __syncthreads();                       // B4
    if (wv < 2) write_rowf(8 + wv, outv);
    __syncthreads();                       // B5: RDA tile complete

    // ---- MFMA implicit-GEMM K-loop (reads slots [0..9][0..17], stride 20)
    float4v acc[2][4];
    #pragma unroll
    for (int i = 0; i < 2; ++i)
        #pragma unroll
        for (int j = 0; j < 4; ++j) acc[i][j] = (float4v)0.f;

    const short* Wp = (const short*)Wpk;
    const int boff = l15*32 + lq*8;        // B-frag offset within a K-step

    // software-pipelined B-fragments: one exposed L2 latency, not 18
    short8 bcur[4], bnxt[4];
    #pragma unroll
    for (int nt = 0; nt < 4; ++nt)
        bcur[nt] = *(const short8*)(Wp + nt*512 + boff);

    #pragma unroll
    for (int s = 0; s < 18; ++s) {
        if (s < 17) {
            #pragma unroll
            for (int nt = 0; nt < 4; ++nt)
                bnxt[nt] = *(const short8*)(Wp + (size_t)(s+1)*2048 + nt*512 + boff);
        }
        const int t = s >> 1, hf = s & 1;
        const int dh = t / 3, dwx = t % 3;
        short8 afr[2];
        #pragma unroll
        for (int mt = 0; mt < 2; ++mt) {
            const int r = wv*2 + mt + dh;
            const int w = l15 + dwx;
            const int chunk = (hf*4 + lq) ^ (w & 7);
            afr[mt] = *(const short8*)(sA + ((r*20 + w)*64 + chunk*8));
        }
        #pragma unroll
        for (int mt = 0; mt < 2; ++mt)
            #pragma unroll
            for (int nt = 0; nt < 4; ++nt)
                acc[mt][nt] = __builtin_amdgcn_mfma_f32_16x16x32_bf16(
                    afr[mt], bcur[nt], acc[mt][nt], 0, 0, 0);
        #pragma unroll
        for (int nt = 0; nt < 4; ++nt) bcur[nt] = bnxt[nt];
    }

    // ---- epilogue
    float bs[4], cwv[4], cbv = 0.f;
    #pragma unroll
    for (int nt = 0; nt < 4; ++nt) bs[nt] = bias[nt*16 + l15];
    if (MODE == 0) {
        #pragma unroll
        for (int nt = 0; nt < 4; ++nt) cwv[nt] = Gcw[nt*16 + l15];
        cbv = Gcb[0];
    }

    #pragma unroll
    for (int mt = 0; mt < 2; ++mt) {
        const int pr = wv*2 + mt;              // 0..7
        if (MODE == 0) {
            float vv[4][4];
            #pragma unroll
            for (int nt = 0; nt < 4; ++nt)
                #pragma unroll
                for (int rg = 0; rg < 4; ++rg)
                    vv[nt][rg] = leaky(acc[mt][nt][rg] + bs[nt]);
            #pragma unroll
            for (int nt = 0; nt < 4; ++nt) {
                const int n = nt*16 + l15;
                #pragma unroll
                for (int rg = 0; rg < 4; ++rg) {
                    const int pw = lq*4 + rg;
                    OutN[(((size_t)b*H_ + h0 + pr)*W_ + w0 + pw)*64 + n] =
                        __float2bfloat16(vv[nt][rg]);
                }
            }
            // fused rda2 gate: reduce 64 oc = 4 nt (in-lane) x 16 l15 (shfl)
            #pragma unroll
            for (int rg = 0; rg < 4; ++rg) {
                float p = vv[0][rg]*cwv[0] + vv[1][rg]*cwv[1]
                        + vv[2][rg]*cwv[2] + vv[3][rg]*cwv[3];
                p += __shfl_xor(p, 1);
                p += __shfl_xor(p, 2);
                p += __shfl_xor(p, 4);
                p += __shfl_xor(p, 8);
                if (l15 == 0)
                    G2[(size_t)b*HW_ + (size_t)(h0 + pr)*W_ + w0 + lq*4 + rg] =
                        1.f / (1.f + __expf(-(p + cbv)));
            }
        } else {
            #pragma unroll
            for (int nt = 0; nt < 4; ++nt) {
                const int n = nt*16 + l15;
                const size_t base = ((size_t)(b*64 + n)*H_ + h0 + pr)*W_ + w0 + lq*4;
                const float4 xr = *(const float4*)(Xres + base);
                float4 v;
                v.x = acc[mt][nt][0] + bs[nt] + xr.x;
                v.y = acc[mt][nt][1] + bs[nt] + xr.y;
                v.z = acc[mt][nt][2] + bs[nt] + xr.z;
                v.w = acc[mt][nt][3] + bs[nt] + xr.w;
                *(float4*)(OutF + base) = v;
            }
        }
    }
}

// ---------------------------------------------------------------------------
extern "C" void kernel_launch(void* const* d_in, const int* in_sizes, int n_in,
                              void* d_out, int out_size, void* d_ws, size_t ws_size,
                              hipStream_t stream)
{
    const float* x       = (const float*)d_in[0];
    const float* d       = (const float*)d_in[1];
    const float* da1_k1  = (const float*)d_in[2];
    const float* da1_k2  = (const float*)d_in[3];
    const float* da1_cw  = (const float*)d_in[4];
    const float* da1_cb  = (const float*)d_in[5];
    const float* da2_k1  = (const float*)d_in[6];
    const float* da2_k2  = (const float*)d_in[7];
    const float* da2_cw  = (const float*)d_in[8];
    const float* da2_cb  = (const float*)d_in[9];
    const float* conv1_w = (const float*)d_in[10];
    const float* conv1_b = (const float*)d_in[11];
    const float* conv2_w = (const float*)d_in[12];
    const float* conv2_b = (const float*)d_in[13];
    float* out = (float*)d_out;

    __hip_bfloat16* bufA = (__hip_bfloat16*)d_ws;      // NTOT_ bf16
    __hip_bfloat16* bufB = bufA + NTOT_;               // NTOT_ bf16
    float* kernA = (float*)(bufB + NTOT_);             // 16*576 fp32
    float* kernB = kernA + 16*576;
    __hip_bfloat16* wpk1 = (__hip_bfloat16*)(kernB + 16*576);  // 18*64*32
    __hip_bfloat16* wpk2 = wpk1 + 18*64*32;
    float* G1 = (float*)(wpk2 + 18*64*32);             // B*HW fp32
    float* G2 = G1 + (size_t)B_*HW_;                   // B*HW fp32

    // merged setup: pre (+rda1 gate) | dyn MLPs | weight prepack
    k_setup<<<dim3(4228), dim3(256), 0, stream>>>(
        x, da1_cw, da1_cb, bufA, G1,
        d, da1_k1, da1_k2, da2_k1, da2_k2, kernA, kernB,
        conv1_w, conv2_w, wpk1, wpk2);
    // fused rda1 + conv1 (+leaky, + rda2 gate): bufA -> bufB (NHWC bf16), G2
    k_rda_conv<0><<<dim3(128, B_), dim3(256), 0, stream>>>(
        bufA, kernA, G1, wpk1, conv1_b, nullptr, da2_cw, da2_cb, bufB, nullptr, G2);
    // fused rda2 + conv2 + x residual -> out (NCHW fp32)
    k_rda_conv<1><<<dim3(128, B_), dim3(256), 0, stream>>>(
        bufB, kernB, G2, wpk2, conv2_b, x, nullptr, nullptr, nullptr, out, nullptr);
}